// Round 3
// baseline (267.251 us; speedup 1.0000x reference)
//
#include <hip/hip_runtime.h>
#include <math.h>

// ---------------------------------------------------------------------------
// SphericalConvCodec. Decision-critical path (encoder + VQ argmin) in fp64 to
// match the fp64 numpy reference exactly; decoder fp32.
// NOTE: setup_inputs() dict order is x,w1,b1,w2,b2,w3,b3,d1w,d1b,d2w,d2b,
// d3w,d3b and THEN codebook (added after the literal) -> codebook = d_in[13].
// ws layout (byte offsets):
#define WSB_Q64   0u         // 32768*12 double  (3145728 B)
#define WSB_QZ    3145728u   // 32768*12 float   (1572864 B)
#define WSB_KEYS  4718592u   // 32768 u64        (262144 B)
#define WSB_CCH   4980736u   // 8192 double      (65536 B)
#define WSB_W1D   5046272u   // 64 double
#define WSB_W2D   5046784u   // 2048 double [k][o][c]
#define WSB_W3D   5063168u   // 1536 double [q][j][o]
#define WSB_B1D   5075456u   // 16 double
#define WSB_B2D   5075584u   // 32 double
#define WSB_B3D   5075840u   // 12 double
#define WSB_D1R   5075936u   // 1536 float [p][o][c]
#define WSB_D2R   5082080u   // 2048 float [k][o][c]
#define WSB_D3R   5090272u   // 64 float  [k][c]

__device__ __forceinline__ float dot4(float4 a, float4 b) {
  return fmaf(a.x, b.x, fmaf(a.y, b.y, fmaf(a.z, b.z, a.w * b.w)));
}
__device__ __forceinline__ float relu(float v) { return v > 0.f ? v : 0.f; }

// ---------------------------------------------------------------------------
// prep: zero keys; cchalf = 0.5*|c|^2 fp64; block 0 repacks weights
__global__ __launch_bounds__(256) void k_prep(
    const float* __restrict__ w1, const float* __restrict__ b1,
    const float* __restrict__ w2, const float* __restrict__ b2,
    const float* __restrict__ w3, const float* __restrict__ b3,
    const float* __restrict__ cbk, const float* __restrict__ d1w,
    const float* __restrict__ d2w, const float* __restrict__ d3w,
    unsigned long long* __restrict__ keys, double* __restrict__ cch,
    double* __restrict__ w1d, double* __restrict__ w2d,
    double* __restrict__ w3d, double* __restrict__ b1d,
    double* __restrict__ b2d, double* __restrict__ b3d,
    float* __restrict__ d1r, float* __restrict__ d2r,
    float* __restrict__ d3r) {
  int gid = blockIdx.x * 256 + threadIdx.x;  // grid 128 -> 32768
  keys[gid] = 0ull;
  if (gid < 8192) {
    double s = 0.0;
#pragma unroll
    for (int d = 0; d < 12; d++) {
      double c = (double)cbk[gid * 12 + d];
      s = fma(c, c, s);
    }
    cch[gid] = 0.5 * s;
  }
  if (blockIdx.x == 0) {
    int t = threadIdx.x;
    for (int i = t; i < 64; i += 256) w1d[i] = (double)w1[i];
    for (int i = t; i < 16; i += 256) b1d[i] = (double)b1[i];
    for (int i = t; i < 32; i += 256) b2d[i] = (double)b2[i];
    for (int i = t; i < 12; i += 256) b3d[i] = (double)b3[i];
    for (int i = t; i < 2048; i += 256) {  // w2d[k][o][c] = w2[o][c][k]
      int k = i >> 9, o = (i >> 4) & 31, c = i & 15;
      w2d[i] = (double)w2[o * 64 + c * 4 + k];
    }
    for (int i = t; i < 1536; i += 256) {  // w3d[q][j][o] = w3[j][o][q]
      int q = i / 384, r = i % 384, j = r >> 5, o = r & 31;
      w3d[i] = (double)w3[j * 128 + o * 4 + q];
    }
    for (int i = t; i < 1536; i += 256) {  // d1r[p][o][c] = d1w[c][o][p]
      int p = i / 384, r = i % 384, o = r / 12, c = r % 12;
      d1r[i] = d1w[c * 128 + o * 4 + p];
    }
    for (int i = t; i < 2048; i += 256) {  // d2r[k][o][c] = d2w[c][o][k]
      int k = i >> 9, o = (i >> 5) & 15, c = i & 31;
      d2r[i] = d2w[c * 64 + o * 4 + k];
    }
    for (int i = t; i < 64; i += 256) {    // d3r[k][c] = d3w[c][k]
      int k = i >> 4, c = i & 15;
      d3r[i] = d3w[c * 4 + k];
    }
  }
}

// ---------------------------------------------------------------------------
// encoder, fp64: wave = conv2/conv3 quarter, lane = window
__global__ __launch_bounds__(256) void k_enc(
    const float* __restrict__ x, const double* __restrict__ w1d,
    const double* __restrict__ w2d, const double* __restrict__ w3d,
    const double* __restrict__ b1d, const double* __restrict__ b2d,
    const double* __restrict__ b3d, float* __restrict__ cont_out,
    double* __restrict__ q64out) {
  int t = threadIdx.x;
  int wave = t >> 6, lane = t & 63;
  int win = blockIdx.x * 64 + lane;  // grid 512 -> 32768
  int n = win >> 4, l = win & 15;
  const float* xb = x + n * 1024 + l * 64 + wave * 16;

  double h2[32];
#pragma unroll
  for (int o = 0; o < 32; o++) h2[o] = b2d[o];

#pragma unroll 1
  for (int k = 0; k < 4; k++) {
    float4 xv = *reinterpret_cast<const float4*>(xb + 4 * k);
    double x0 = (double)xv.x, x1 = (double)xv.y;
    double x2 = (double)xv.z, x3 = (double)xv.w;
    double h1[16];
#pragma unroll
    for (int c = 0; c < 16; c++) {
      const double* wv = w1d + 4 * c;
      double s = b1d[c];
      s = fma(x0, wv[0], s); s = fma(x1, wv[1], s);
      s = fma(x2, wv[2], s); s = fma(x3, wv[3], s);
      h1[c] = s > 0.0 ? s : 0.0;
    }
    const double* w2k = w2d + k * 512;
#pragma unroll
    for (int o = 0; o < 32; o++) {
      const double* wp = w2k + o * 16;
      double s = h2[o];
#pragma unroll
      for (int c = 0; c < 16; c++) s = fma(h1[c], wp[c], s);
      h2[o] = s;
    }
  }
#pragma unroll
  for (int o = 0; o < 32; o++) h2[o] = h2[o] > 0.0 ? h2[o] : 0.0;

  double pc[12];
  const double* w3q = w3d + wave * 384;
#pragma unroll
  for (int j = 0; j < 12; j++) {
    const double* wp = w3q + j * 32;
    double s = 0.0;
#pragma unroll
    for (int o = 0; o < 32; o++) s = fma(h2[o], wp[o], s);
    pc[j] = s;
  }

  __shared__ double red[4][64][13];  // pad 13: break 96B stride conflicts
#pragma unroll
  for (int j = 0; j < 12; j++) red[wave][lane][j] = pc[j];
  __syncthreads();

  if (wave == 0) {
    double cont[12], ss = 0.0;
#pragma unroll
    for (int j = 0; j < 12; j++) {
      double v = b3d[j] + ((red[0][lane][j] + red[1][lane][j]) +
                           (red[2][lane][j] + red[3][lane][j]));
      cont[j] = v;
      ss = fma(v, v, ss);
    }
    double nrm = sqrt(ss);
    if (nrm < 1e-12) nrm = 1e-12;
#pragma unroll
    for (int j = 0; j < 12; j++) {
      double qv = cont[j] / nrm;
      cont_out[n * 192 + j * 16 + l] = (float)qv;
      q64out[(size_t)win * 12 + j] = qv;
    }
  }
}

// ---------------------------------------------------------------------------
// VQ: fp32 scan + running-max filter (delta covers all fp32 noise), exact
// fp64 rescoring of candidates, u64 atomicMax combine (48-bit score key,
// low 16 bits = 8191-idx so ties pick smallest index like jnp.argmin).
#define CBC 512
#define DELTA 1e-4f
#define SCALE46 70368744177664.0  // 2^46

__global__ __launch_bounds__(256) void k_vq(
    const double* __restrict__ q64, const float* __restrict__ codebook,
    const double* __restrict__ cchalf,
    unsigned long long* __restrict__ keys) {
  int cc = blockIdx.x & 15;   // code chunk
  int qc = blockIdx.x >> 4;   // query chunk (0..63), 512 queries each
  __shared__ float cb[CBC * 12];  // 24 KB
  int t = threadIdx.x;
  {
    const float4* src = reinterpret_cast<const float4*>(codebook + cc * CBC * 12);
    float4* dst = reinterpret_cast<float4*>(cb);
#pragma unroll
    for (int i = 0; i < 6; i++) dst[t + i * 256] = src[t + i * 256];
  }
  __syncthreads();

  int q0 = qc * 512 + t, q1 = q0 + 256;
  double qA64[12], qB64[12];
  float qA[12], qB[12];
#pragma unroll
  for (int d = 0; d < 12; d++) {
    qA64[d] = q64[(size_t)q0 * 12 + d]; qA[d] = (float)qA64[d];
    qB64[d] = q64[(size_t)q1 * 12 + d]; qB[d] = (float)qB64[d];
  }
  float4 A0 = make_float4(qA[0], qA[1], qA[2], qA[3]);
  float4 A1 = make_float4(qA[4], qA[5], qA[6], qA[7]);
  float4 A2 = make_float4(qA[8], qA[9], qA[10], qA[11]);
  float4 B0 = make_float4(qB[0], qB[1], qB[2], qB[3]);
  float4 B1 = make_float4(qB[4], qB[5], qB[6], qB[7]);
  float4 B2 = make_float4(qB[8], qB[9], qB[10], qB[11]);

  float mda = -3.f, mdb = -3.f;   // running (max - DELTA)
  unsigned long long kbA = 0ull, kbB = 0ull;

#pragma unroll 1
  for (int g = 0; g < 8; g++) {
    unsigned long long mask = 0ull;
#pragma unroll 4
    for (int j2 = 0; j2 < 64; j2++) {
      const float* cp = cb + (g * 64 + j2) * 12;
      float4 c0 = *reinterpret_cast<const float4*>(cp);
      float4 c1 = *reinterpret_cast<const float4*>(cp + 4);
      float4 c2 = *reinterpret_cast<const float4*>(cp + 8);
      float sa = (dot4(A0, c0) + dot4(A1, c1)) + dot4(A2, c2);
      float sb = (dot4(B0, c0) + dot4(B1, c1)) + dot4(B2, c2);
      bool trig = (sa >= mda) || (sb >= mdb);
      // shift-register: bit inserted at 63 lands at position j2 after loop
      mask = (mask >> 1) | (trig ? 0x8000000000000000ull : 0ull);
      mda = fmaxf(mda, sa - DELTA);
      mdb = fmaxf(mdb, sb - DELTA);
    }
    while (mask) {
      int j2 = __builtin_ctzll(mask);
      mask &= mask - 1;
      int j = g * 64 + j2, jg = cc * CBC + j;
      const float* cp = cb + j * 12;
      double sA = 0.0, sB = 0.0;
#pragma unroll
      for (int d = 0; d < 12; d++) {
        double cd = (double)cp[d];
        sA = fma(qA64[d], cd, sA);
        sB = fma(qB64[d], cd, sB);
      }
      double cch = cchalf[jg];
      unsigned long long eA = (unsigned long long)((sA - cch + 2.0) * SCALE46);
      unsigned long long eB = (unsigned long long)((sB - cch + 2.0) * SCALE46);
      unsigned long long keyA = (eA << 16) | (unsigned)(8191 - jg);
      unsigned long long keyB = (eB << 16) | (unsigned)(8191 - jg);
      kbA = kbA > keyA ? kbA : keyA;
      kbB = kbB > keyB ? kbB : keyB;
    }
  }
  atomicMax(&keys[q0], kbA);
  atomicMax(&keys[q1], kbB);
}

// ---------------------------------------------------------------------------
// unpack: key -> idx -> gather codebook row
__global__ __launch_bounds__(256) void k_unpack(
    const unsigned long long* __restrict__ keys,
    const float* __restrict__ codebook, float* __restrict__ quant_out,
    float* __restrict__ qz) {
  int q = blockIdx.x * 256 + threadIdx.x;  // grid 128 -> 32768
  int gidx = 8191 - (int)(keys[q] & 0xFFFFull);
  int n = q >> 4, l = q & 15;
  const float* cp = codebook + gidx * 12;
#pragma unroll
  for (int c = 0; c < 12; c++) {
    float v = cp[c];
    quant_out[n * 192 + c * 16 + l] = v;
    qz[q * 12 + c] = v;
  }
}

// ---------------------------------------------------------------------------
// decoder (fp32): wave = deconv1 sub-position, lane = window
__global__ __launch_bounds__(256) void k_dec(
    const float* __restrict__ qz, const float* __restrict__ d1r,
    const float* __restrict__ d2r, const float* __restrict__ d3r,
    const float* __restrict__ d1b, const float* __restrict__ d2b,
    const float* __restrict__ d3b, float* __restrict__ rec) {
  int t = threadIdx.x;
  int p2 = t >> 6, lane = t & 63;
  int win = blockIdx.x * 64 + lane;  // grid 512 -> 32768
  const float4* qp = reinterpret_cast<const float4*>(qz + win * 12);
  float4 q0 = qp[0], q1 = qp[1], q2 = qp[2];

  const float* d1p = d1r + p2 * 384;
  float y1[32];
#pragma unroll
  for (int o = 0; o < 32; o++) {
    const float4* wp = reinterpret_cast<const float4*>(d1p + o * 12);
    float4 a0 = wp[0], a1 = wp[1], a2 = wp[2];
    float s = d1b[o];
    s = fmaf(q0.x, a0.x, s); s = fmaf(q0.y, a0.y, s);
    s = fmaf(q0.z, a0.z, s); s = fmaf(q0.w, a0.w, s);
    s = fmaf(q1.x, a1.x, s); s = fmaf(q1.y, a1.y, s);
    s = fmaf(q1.z, a1.z, s); s = fmaf(q1.w, a1.w, s);
    s = fmaf(q2.x, a2.x, s); s = fmaf(q2.y, a2.y, s);
    s = fmaf(q2.z, a2.z, s); s = fmaf(q2.w, a2.w, s);
    y1[o] = relu(s);
  }

  float d3bias = d3b[0];
#pragma unroll 1
  for (int k = 0; k < 4; k++) {
    const float* d2k = d2r + k * 512;
    float y2[16];
#pragma unroll
    for (int o = 0; o < 16; o++) {
      const float4* wp = reinterpret_cast<const float4*>(d2k + o * 32);
      float s = d2b[o];
#pragma unroll
      for (int g = 0; g < 8; g++) {
        float4 a = wp[g];
        s = fmaf(y1[4 * g + 0], a.x, s); s = fmaf(y1[4 * g + 1], a.y, s);
        s = fmaf(y1[4 * g + 2], a.z, s); s = fmaf(y1[4 * g + 3], a.w, s);
      }
      y2[o] = relu(s);
    }
    float ov[4];
#pragma unroll
    for (int kk = 0; kk < 4; kk++) {
      const float4* wp = reinterpret_cast<const float4*>(d3r + kk * 16);
      float s = d3bias;
#pragma unroll
      for (int g = 0; g < 4; g++) {
        float4 a = wp[g];
        s = fmaf(y2[4 * g + 0], a.x, s); s = fmaf(y2[4 * g + 1], a.y, s);
        s = fmaf(y2[4 * g + 2], a.z, s); s = fmaf(y2[4 * g + 3], a.w, s);
      }
      ov[kk] = s;
    }
    *reinterpret_cast<float4*>(rec + win * 64 + p2 * 16 + k * 4) =
        make_float4(ov[0], ov[1], ov[2], ov[3]);
  }
}

// ---------------------------------------------------------------------------
extern "C" void kernel_launch(void* const* d_in, const int* in_sizes, int n_in,
                              void* d_out, int out_size, void* d_ws,
                              size_t ws_size, hipStream_t stream) {
  const float* x  = (const float*)d_in[0];
  const float* w1 = (const float*)d_in[1];
  const float* b1 = (const float*)d_in[2];
  const float* w2 = (const float*)d_in[3];
  const float* b2 = (const float*)d_in[4];
  const float* w3 = (const float*)d_in[5];
  const float* b3 = (const float*)d_in[6];
  // codebook added to the inputs dict AFTER the decoder weights -> index 13.
  // Defensive: codebook is the unique 98304-element input.
  int cb_idx = (in_sizes[13] == 98304) ? 13 : 7;
  int dbase = (cb_idx == 13) ? 7 : 8;
  const float* cbk = (const float*)d_in[cb_idx];
  const float* d1w = (const float*)d_in[dbase + 0];
  const float* d1b = (const float*)d_in[dbase + 1];
  const float* d2w = (const float*)d_in[dbase + 2];
  const float* d2b = (const float*)d_in[dbase + 3];
  const float* d3w = (const float*)d_in[dbase + 4];
  const float* d3b = (const float*)d_in[dbase + 5];

  float* out = (float*)d_out;
  float* rec = out;                 // (2048,1,1024)
  float* cont_out = out + 2097152;  // (2048,12,16)
  float* quant_out = out + 2490368; // (2048,12,16)

  char* wsb = (char*)d_ws;
  double* q64 = (double*)(wsb + WSB_Q64);
  float* qz = (float*)(wsb + WSB_QZ);
  unsigned long long* keys = (unsigned long long*)(wsb + WSB_KEYS);
  double* cch = (double*)(wsb + WSB_CCH);
  double* w1d = (double*)(wsb + WSB_W1D);
  double* w2d = (double*)(wsb + WSB_W2D);
  double* w3d = (double*)(wsb + WSB_W3D);
  double* b1d = (double*)(wsb + WSB_B1D);
  double* b2d = (double*)(wsb + WSB_B2D);
  double* b3d = (double*)(wsb + WSB_B3D);
  float* d1r = (float*)(wsb + WSB_D1R);
  float* d2r = (float*)(wsb + WSB_D2R);
  float* d3r = (float*)(wsb + WSB_D3R);

  k_prep<<<128, 256, 0, stream>>>(w1, b1, w2, b2, w3, b3, cbk, d1w, d2w, d3w,
                                  keys, cch, w1d, w2d, w3d, b1d, b2d, b3d,
                                  d1r, d2r, d3r);
  k_enc<<<512, 256, 0, stream>>>(x, w1d, w2d, w3d, b1d, b2d, b3d, cont_out,
                                 q64);
  k_vq<<<1024, 256, 0, stream>>>(q64, cbk, cch, keys);
  k_unpack<<<128, 256, 0, stream>>>(keys, cbk, quant_out, qz);
  k_dec<<<512, 256, 0, stream>>>(qz, d1r, d2r, d3r, d1b, d2b, d3b, rec);
}